// Round 2
// baseline (4554.720 us; speedup 1.0000x reference)
//
#include <hip/hip_runtime.h>
#include <hip/hip_bf16.h>

#define EMBED   300
#define HIDDEN  256
#define BATCH   64
#define SEQ     256
#define NG      1024          // 4*HIDDEN
#define NBLK    64            // 16 L1-rec + 16 L2-rec + 32 helpers
#define EPOCHS  258

typedef __attribute__((ext_vector_type(8))) short  short8;   // 8 bf16
typedef __attribute__((ext_vector_type(4))) float  f32x4;

__device__ inline unsigned short f2bf(float f) {
    unsigned u = __builtin_bit_cast(unsigned, f);
    return (unsigned short)((u + 0x7FFFu + ((u >> 16) & 1u)) >> 16);   // RNE
}
__device__ inline float bf2f(unsigned short h) {
    unsigned u = (unsigned)h << 16;
    return __builtin_bit_cast(float, u);
}
__device__ inline float sigm(float x)  { return 1.0f / (1.0f + __expf(-x)); }
__device__ inline float tanh_(float x) { return 2.0f / (1.0f + __expf(-2.0f * x)) - 1.0f; }

__device__ inline int swzb(int c, int base) { return base ^ (((c >> 1) & 3) << 4); }

// two-level barrier: 8 leaf counters (one/128B line) + root counter + sense
__device__ inline void bar_arrive(unsigned* bar, unsigned ls) {
    int leaf = blockIdx.x >> 3;                     // 8 groups of 8 blocks
    unsigned o = __hip_atomic_fetch_add(&bar[leaf * 32], 1u,
                    __ATOMIC_ACQ_REL, __HIP_MEMORY_SCOPE_AGENT);
    if (o == 7) {
        __hip_atomic_store(&bar[leaf * 32], 0u, __ATOMIC_RELAXED, __HIP_MEMORY_SCOPE_AGENT);
        unsigned r = __hip_atomic_fetch_add(&bar[256], 1u,
                        __ATOMIC_ACQ_REL, __HIP_MEMORY_SCOPE_AGENT);
        if (r == 7) {
            __hip_atomic_store(&bar[256], 0u, __ATOMIC_RELAXED, __HIP_MEMORY_SCOPE_AGENT);
            __hip_atomic_store(&bar[288], ls, __ATOMIC_RELEASE, __HIP_MEMORY_SCOPE_AGENT);
        }
    }
}
__device__ inline bool bar_wait(unsigned* bar, unsigned ls) {
    int n = 0;
    while (__hip_atomic_load(&bar[288], __ATOMIC_ACQUIRE, __HIP_MEMORY_SCOPE_AGENT) != ls) {
        if (++n > (1 << 20)) return false;          // failsafe: never hang the bench
    }
    return true;
}

#define MFMA(a, b, c) __builtin_amdgcn_mfma_f32_16x16x32_bf16((a), (b), (c), 0, 0, 0)

__global__ __launch_bounds__(256, 1) void lstm_fused(
    const int*   __restrict__ xin,   // [64][256]
    const float* __restrict__ emb,   // [50000][300]
    const float* __restrict__ W0, const float* __restrict__ b0,   // [556][1024],[1024]
    const float* __restrict__ W1, const float* __restrict__ b1,   // [512][1024],[1024]
    unsigned*       __restrict__ bar,
    unsigned short* __restrict__ h1buf,   // [2][64][256] bf16
    unsigned short* __restrict__ h2buf,   // [2][64][256] bf16
    float*          __restrict__ ring,    // [4][64][1024] f32 (gx1 ring, bias folded)
    float*          __restrict__ out)     // [64][256] f32
{
    extern __shared__ unsigned short lds[];   // 40960 B
    const int tid = threadIdx.x, bid = blockIdx.x;
    const int w = tid >> 6, lane = tid & 63, l15 = lane & 15, q = lane >> 4;
    const int bbase = w * 16, arow = bbase + l15;
    const int role = (bid < 16) ? 0 : (bid < 32 ? 1 : 2);   // L1-rec, L2-rec, helper
    const int u0  = (bid & 15) * 16;          // roles 0/1 only
    const int u   = u0 + l15;
    const int hc0 = (bid - 32) * 32;          // role 2 only

    // ---- zero h buffers (both parities) : 2 x 64KB over first 32 blocks ----
    {
        int g = bid * 256 + tid;
        if (g < 8192) {
            ((unsigned long long*)h1buf)[g] = 0ULL;
            ((unsigned long long*)h2buf)[g] = 0ULL;
        }
    }

    // ---- stage LDS + load register fragments per role ----
    short8 bfragR[8][4];          // recurrent W (roles 0/1)
    float  bias_r[4];             // role 1
    float  biasH[2];              // role 2

    if (role < 2) {
        const float* Wl = (role == 1) ? W1 : W0;
        const int    ro = (role == 1) ? HIDDEN : EMBED;   // recurrent row offset
        #pragma unroll
        for (int s = 0; s < 8; ++s)
            #pragma unroll
            for (int nt = 0; nt < 4; ++nt)
                #pragma unroll
                for (int e2 = 0; e2 < 8; ++e2) {
                    int k = ro + s * 32 + q * 8 + e2;
                    bfragR[s][nt][e2] = (short)f2bf(Wl[(long)k * NG + nt * 256 + u0 + l15]);
                }
        if (role == 1) {
            #pragma unroll
            for (int nt = 0; nt < 4; ++nt) bias_r[nt] = b1[nt * 256 + u0 + l15];
            // stage W1 rows 0..255 (h1 contribution), 64 cols, 8 regions x 4KB
            for (int idx = tid; idx < 8 * 64 * 32; idx += 256) {
                int k = idx >> 6, c = idx & 63;
                int col = (c >> 4) * 256 + u0 + (c & 15);
                int s = k >> 5, kk = k & 31;
                *(unsigned short*)((char*)lds + s * 4096 + swzb(c, c * 64 + kk * 2)) =
                    f2bf(W1[(long)k * NG + col]);
            }
        }
    } else {
        #pragma unroll
        for (int gi = 0; gi < 2; ++gi) biasH[gi] = b0[hc0 + gi * 16 + l15];
        // stage W0 x-part, 32 cols, hi (s=0..9) + lo (s=10..19), 20 regions x 2KB
        for (int idx = tid; idx < 20 * 32 * 32; idx += 256) {
            int k = idx >> 5, c = idx & 31;        // k: 0..639, c: 0..31
            int s = k >> 5, kk = k & 31;
            int row = (s >= 10) ? (k - 320) : k;   // rows 300..319 harmless (A zeroed)
            float v = W0[(long)row * NG + hc0 + c];
            unsigned short hv = f2bf(v);
            if (s >= 10) hv = f2bf(v - bf2f(hv));  // lo residual
            *(unsigned short*)((char*)lds + s * 2048 + swzb(c, c * 64 + kk * 2)) = hv;
        }
    }
    __syncthreads();   // LDS staged (intra-block)

    // ---- helper: produce gx1[t] into ring slot t&3 (bias folded, f32) ----
    auto produce = [&](int t) {
        int xid = xin[arow * SEQ + t];
        const float* erow = emb + (long)xid * EMBED;
        short8 ac[10];
        #pragma unroll
        for (int s = 0; s < 10; ++s) {
            int kb = s * 32 + q * 8;
            #pragma unroll
            for (int hh = 0; hh < 2; ++hh) {
                int k4 = kb + hh * 4;
                if (k4 < EMBED) {
                    f32x4 v = *(const f32x4*)(erow + k4);
                    #pragma unroll
                    for (int e2 = 0; e2 < 4; ++e2) ac[s][hh * 4 + e2] = (short)f2bf(v[e2]);
                } else {
                    #pragma unroll
                    for (int e2 = 0; e2 < 4; ++e2) ac[s][hh * 4 + e2] = 0;
                }
            }
        }
        f32x4 accg[2];
        #pragma unroll
        for (int gi = 0; gi < 2; ++gi)
            accg[gi] = (f32x4){biasH[gi], biasH[gi], biasH[gi], biasH[gi]};
        #pragma unroll
        for (int s = 0; s < 20; ++s) {
            short8 a = ac[(s < 10) ? s : s - 10];
            #pragma unroll
            for (int gi = 0; gi < 2; ++gi) {
                int c = gi * 16 + l15;
                short8 b = *(const short8*)((char*)lds + s * 2048 + swzb(c, c * 64 + q * 16));
                accg[gi] = MFMA(a, b, accg[gi]);
            }
        }
        float* dst = ring + (long)(t & 3) * (64 * NG);
        #pragma unroll
        for (int gi = 0; gi < 2; ++gi)
            #pragma unroll
            for (int rr = 0; rr < 4; ++rr)
                dst[(bbase + q * 4 + rr) * NG + hc0 + gi * 16 + l15] = accg[gi][rr];
    };

    if (role == 2) { produce(0); produce(1); }   // prologue: t=0,1

    // ---- init barrier (publish zeros + prologue ring) ----
    unsigned ls = 0;
    bool alive = true;
    __threadfence();
    __syncthreads();
    ls ^= 1;
    if (tid == 0 && alive) { bar_arrive(bar, ls); alive = bar_wait(bar, ls); }
    __syncthreads();
    __threadfence();

    float  c4[4] = {0.f, 0.f, 0.f, 0.f};
    f32x4  accx[4];     // role 1: precomputed h1@W1x + b1

    for (int e = 0; e < EPOCHS; ++e) {
        // ================= main (critical path) =================
        if (role == 0 && e <= 255) {
            const unsigned short* hr = h1buf + ((e - 1) & 1) * 16384;
            unsigned short*       hw = h1buf + (e & 1) * 16384;
            const float* gsrc = ring + (long)(e & 3) * (64 * NG);
            f32x4 acc[4];
            #pragma unroll
            for (int nt = 0; nt < 4; ++nt)
                #pragma unroll
                for (int rr = 0; rr < 4; ++rr)
                    acc[nt][rr] = gsrc[(bbase + q * 4 + rr) * NG + nt * 256 + u0 + l15];
            short8 a8[8];
            #pragma unroll
            for (int s = 0; s < 8; ++s)
                a8[s] = *(const short8*)(hr + arow * HIDDEN + s * 32 + q * 8);
            #pragma unroll
            for (int s = 0; s < 8; ++s)
                #pragma unroll
                for (int nt = 0; nt < 4; ++nt)
                    acc[nt] = MFMA(a8[s], bfragR[s][nt], acc[nt]);
            #pragma unroll
            for (int rr = 0; rr < 4; ++rr) {
                int b = bbase + q * 4 + rr;
                float iv = sigm(acc[0][rr]);
                float jv = tanh_(acc[1][rr]);
                float fv = sigm(acc[2][rr] + 1.0f);
                float ov = sigm(acc[3][rr]);
                float cn = c4[rr] * fv + iv * jv;
                c4[rr] = cn;
                hw[b * HIDDEN + u] = f2bf(tanh_(cn) * ov);
            }
        } else if (role == 1 && e >= 2) {
            const unsigned short* hr = h2buf + ((e - 1) & 1) * 16384;
            unsigned short*       hw = h2buf + (e & 1) * 16384;
            f32x4 acc[4];
            #pragma unroll
            for (int nt = 0; nt < 4; ++nt) acc[nt] = accx[nt];
            short8 a8[8];
            #pragma unroll
            for (int s = 0; s < 8; ++s)
                a8[s] = *(const short8*)(hr + arow * HIDDEN + s * 32 + q * 8);
            #pragma unroll
            for (int s = 0; s < 8; ++s)
                #pragma unroll
                for (int nt = 0; nt < 4; ++nt)
                    acc[nt] = MFMA(a8[s], bfragR[s][nt], acc[nt]);
            #pragma unroll
            for (int rr = 0; rr < 4; ++rr) {
                int b = bbase + q * 4 + rr;
                float iv = sigm(acc[0][rr]);
                float jv = tanh_(acc[1][rr]);
                float fv = sigm(acc[2][rr] + 1.0f);
                float ov = sigm(acc[3][rr]);
                float cn = c4[rr] * fv + iv * jv;
                c4[rr] = cn;
                float hn = tanh_(cn) * ov;
                hw[b * HIDDEN + u] = f2bf(hn);
                if (e == 257) out[b * HIDDEN + u] = hn;
            }
        }

        // ================= barrier with slack-window work =================
        __threadfence();
        __syncthreads();
        ls ^= 1;
        if (tid == 0 && alive) bar_arrive(bar, ls);

        if (role == 1 && e >= 1 && e <= 256) {
            // accx for t2' = e-1 : b1 + h1[e-1] @ W1x  (W1 rows 0..255, from LDS)
            const unsigned short* h1r = h1buf + ((e - 1) & 1) * 16384;
            #pragma unroll
            for (int nt = 0; nt < 4; ++nt)
                accx[nt] = (f32x4){bias_r[nt], bias_r[nt], bias_r[nt], bias_r[nt]};
            #pragma unroll
            for (int s = 0; s < 8; ++s) {
                short8 a = *(const short8*)(h1r + arow * HIDDEN + s * 32 + q * 8);
                #pragma unroll
                for (int nt = 0; nt < 4; ++nt) {
                    int c = nt * 16 + l15;
                    short8 b = *(const short8*)((char*)lds + s * 4096 + swzb(c, c * 64 + q * 16));
                    accx[nt] = MFMA(a, b, accx[nt]);
                }
            }
        } else if (role == 2 && e <= 253) {
            produce(e + 2);
        }

        if (tid == 0 && alive) alive = bar_wait(bar, ls);
        __syncthreads();
        __threadfence();
    }
}

__global__ void ws_too_small_sentinel(float* out, int n) {
    int i = blockIdx.x * 256 + threadIdx.x;
    if (i < n) out[i] = 31337.0f;
}

extern "C" void kernel_launch(void* const* d_in, const int* in_sizes, int n_in,
                              void* d_out, int out_size, void* d_ws, size_t ws_size,
                              hipStream_t stream)
{
    const int*   xin = (const int*)d_in[0];
    const float* emb = (const float*)d_in[1];
    const float* W0  = (const float*)d_in[2];
    const float* b0  = (const float*)d_in[3];
    const float* W1  = (const float*)d_in[4];
    const float* b1  = (const float*)d_in[5];
    float* out = (float*)d_out;

    // ws layout
    const size_t OFF_BAR  = 0;          // 2048 B (barrier lines)
    const size_t OFF_H1   = 4096;       // 65536 B
    const size_t OFF_H2   = OFF_H1 + 65536;
    const size_t OFF_RING = OFF_H2 + 65536;            // 1 MB
    const size_t NEED     = OFF_RING + (size_t)4 * 64 * NG * 4;

    if (ws_size < NEED) {   // diagnostic sentinel: absmax ~31337 => ws too small
        ws_too_small_sentinel<<<(out_size + 255) / 256, 256, 0, stream>>>(out, out_size);
        return;
    }

    char* ws = (char*)d_ws;
    unsigned*       bar   = (unsigned*)(ws + OFF_BAR);
    unsigned short* h1buf = (unsigned short*)(ws + OFF_H1);
    unsigned short* h2buf = (unsigned short*)(ws + OFF_H2);
    float*          ring  = (float*)(ws + OFF_RING);

    hipMemsetAsync(bar, 0, 2048, stream);
    lstm_fused<<<dim3(NBLK), dim3(256), 40960, stream>>>(
        xin, emb, W0, b0, W1, b1, bar, h1buf, h2buf, ring, out);
}

// Round 3
// 1306.952 us; speedup vs baseline: 3.4850x; 3.4850x over previous
//
#include <hip/hip_runtime.h>

#define EMBED   300
#define HIDDEN  256
#define SEQ     256
#define NG      1024          // 4*HIDDEN
#define EPOCHS  258

typedef __attribute__((ext_vector_type(8))) short  short8;   // 8 bf16
typedef __attribute__((ext_vector_type(4))) float  f32x4;
typedef __attribute__((ext_vector_type(2))) unsigned long long ull2;

__device__ inline unsigned short f2bf(float f) {
    unsigned u = __builtin_bit_cast(unsigned, f);
    return (unsigned short)((u + 0x7FFFu + ((u >> 16) & 1u)) >> 16);   // RNE
}
__device__ inline float bf2f(unsigned short h) {
    unsigned u = (unsigned)h << 16;
    return __builtin_bit_cast(float, u);
}
__device__ inline float sigm(float x)  { return 1.0f / (1.0f + __expf(-x)); }
__device__ inline float tanh_(float x) { return 2.0f / (1.0f + __expf(-2.0f * x)) - 1.0f; }
__device__ inline int swzb(int c, int base) { return base ^ (((c >> 1) & 3) << 4); }

// relaxed agent-scope accesses: coherent at LLC, no L2 flush/invalidate
__device__ inline unsigned ld32a(const unsigned* p) {
    return __hip_atomic_load(p, __ATOMIC_RELAXED, __HIP_MEMORY_SCOPE_AGENT);
}
__device__ inline void st32a(unsigned* p, unsigned v) {
    __hip_atomic_store(p, v, __ATOMIC_RELAXED, __HIP_MEMORY_SCOPE_AGENT);
}
__device__ inline unsigned long long ld64a(const unsigned long long* p) {
    return __hip_atomic_load(p, __ATOMIC_RELAXED, __HIP_MEMORY_SCOPE_AGENT);
}
__device__ inline void st64a(unsigned long long* p, unsigned long long v) {
    __hip_atomic_store(p, v, __ATOMIC_RELAXED, __HIP_MEMORY_SCOPE_AGENT);
}
__device__ inline float ldf32a(const float* p) {
    return __builtin_bit_cast(float, ld32a((const unsigned*)p));
}
__device__ inline void stf32a(float* p, float v) {
    st32a((unsigned*)p, __builtin_bit_cast(unsigned, v));
}
__device__ inline short8 ldh16(const unsigned short* p) {   // 16B coherent load
    ull2 t;
    t.x = ld64a((const unsigned long long*)p);
    t.y = ld64a((const unsigned long long*)p + 1);
    return __builtin_bit_cast(short8, t);
}

#define MFMA(a, b, c) __builtin_amdgcn_mfma_f32_16x16x32_bf16((a), (b), (c), 0, 0, 0)

// Roles: 0-15 L1-rec (u-stripe), 16-31 L2-rec (u-stripe),
//        FULL: 32-47 L2-xpart (u-stripe), 48-79 L1-xpart helpers (hc stripe)
//        !FULL: 32-63 L1-xpart helpers; L2-xpart runs in role-1's slack (round-2 style)
template <bool FULL>
__global__ __launch_bounds__(256, 1) void lstm_fused(
    const int*   __restrict__ xin,
    const float* __restrict__ emb,
    const float* __restrict__ W0, const float* __restrict__ b0,
    const float* __restrict__ W1, const float* __restrict__ b1,
    unsigned*       __restrict__ flags,   // [NB] at 64B stride
    unsigned short* __restrict__ h1buf,   // [2][64][256] bf16
    unsigned short* __restrict__ h2buf,   // [2][64][256] bf16
    float*          __restrict__ ring1,   // [4][64][1024] f32
    float*          __restrict__ ring2,   // [2][64][1024] f32 (FULL only)
    float*          __restrict__ out)     // [64][256] f32
{
    extern __shared__ unsigned short lds[];   // 40960 B
    const int tid = threadIdx.x, bid = blockIdx.x;
    const int w = tid >> 6, lane = tid & 63, l15 = lane & 15, q = lane >> 4;
    const int bbase = w * 16, arow = bbase + l15;

    int role, u0 = 0, hc0 = 0;
    if      (bid < 16) { role = 0; u0 = bid * 16; }
    else if (bid < 32) { role = 1; u0 = (bid - 16) * 16; }
    else if (FULL && bid < 48) { role = 2; u0 = (bid - 32) * 16; }
    else { role = 3; hc0 = (bid - (FULL ? 48 : 32)) * 32; }
    const int u = u0 + l15;

    // zero both parities of h state (coherent stores)
    if (bid < 16)       st64a((unsigned long long*)h1buf + bid * 256 + tid, 0ULL);
    else if (bid < 32)  st64a((unsigned long long*)h2buf + (bid - 16) * 256 + tid, 0ULL);

    // ---- per-role setup ----
    short8 bfragR[8][4];
    float  bias_r[4];
    float  biasH[2];

    if (role == 0 || role == 1) {
        const float* Wl = role ? W1 : W0;
        const int    ro = role ? HIDDEN : EMBED;
        #pragma unroll
        for (int s = 0; s < 8; ++s)
            #pragma unroll
            for (int nt = 0; nt < 4; ++nt)
                #pragma unroll
                for (int e2 = 0; e2 < 8; ++e2) {
                    int k = ro + s * 32 + q * 8 + e2;
                    bfragR[s][nt][e2] = (short)f2bf(Wl[(long)k * NG + nt * 256 + u0 + l15]);
                }
    }
    if ((FULL && role == 2) || (!FULL && role == 1)) {
        #pragma unroll
        for (int nt = 0; nt < 4; ++nt) bias_r[nt] = b1[nt * 256 + u0 + l15];
        // stage W1 rows 0..255 (x-part of layer 2) for this u-stripe: 8 x 4KB
        for (int idx = tid; idx < 8 * 64 * 32; idx += 256) {
            int k = idx >> 6, c = idx & 63;
            int col = (c >> 4) * 256 + u0 + (c & 15);
            int s = k >> 5, kk = k & 31;
            *(unsigned short*)((char*)lds + s * 4096 + swzb(c, c * 64 + kk * 2)) =
                f2bf(W1[(long)k * NG + col]);
        }
    }
    if (role == 3) {
        #pragma unroll
        for (int gi = 0; gi < 2; ++gi) biasH[gi] = b0[hc0 + gi * 16 + l15];
        // stage W0 x-part hi (s=0..9) + lo residual (s=10..19): 20 x 2KB
        for (int idx = tid; idx < 20 * 32 * 32; idx += 256) {
            int k = idx >> 5, c = idx & 31;
            int s = k >> 5, kk = k & 31;
            int row = (s >= 10) ? (k - 320) : k;
            float v = W0[(long)row * NG + hc0 + c];
            unsigned short hv = f2bf(v);
            if (s >= 10) hv = f2bf(v - bf2f(hv));
            *(unsigned short*)((char*)lds + s * 2048 + swzb(c, c * 64 + kk * 2)) = hv;
        }
    }
    __syncthreads();

    // ---- helper: produce gx1[t] into ring1 slot t&3 (bias folded, f32) ----
    auto produce = [&](int t) {
        int xid = xin[arow * SEQ + t];
        const float* erow = emb + (long)xid * EMBED;
        short8 ac[10];
        #pragma unroll
        for (int s = 0; s < 10; ++s) {
            int kb = s * 32 + q * 8;
            #pragma unroll
            for (int hh = 0; hh < 2; ++hh) {
                int k4 = kb + hh * 4;
                if (k4 < EMBED) {
                    f32x4 v = *(const f32x4*)(erow + k4);
                    #pragma unroll
                    for (int e2 = 0; e2 < 4; ++e2) ac[s][hh * 4 + e2] = (short)f2bf(v[e2]);
                } else {
                    #pragma unroll
                    for (int e2 = 0; e2 < 4; ++e2) ac[s][hh * 4 + e2] = 0;
                }
            }
        }
        f32x4 accg[2];
        #pragma unroll
        for (int gi = 0; gi < 2; ++gi)
            accg[gi] = (f32x4){biasH[gi], biasH[gi], biasH[gi], biasH[gi]};
        #pragma unroll
        for (int s = 0; s < 20; ++s) {
            short8 a = ac[(s < 10) ? s : s - 10];
            #pragma unroll
            for (int gi = 0; gi < 2; ++gi) {
                int c = gi * 16 + l15;
                short8 b = *(const short8*)((char*)lds + s * 2048 + swzb(c, c * 64 + q * 16));
                accg[gi] = MFMA(a, b, accg[gi]);
            }
        }
        float* dst = ring1 + (long)(t & 3) * (64 * NG);
        #pragma unroll
        for (int gi = 0; gi < 2; ++gi)
            #pragma unroll
            for (int rr = 0; rr < 4; ++rr)
                stf32a(dst + (bbase + q * 4 + rr) * NG + hc0 + gi * 16 + l15, accg[gi][rr]);
    };

    if (role == 3) { produce(0); produce(1); produce(2); }   // produce-ahead = 3

    // ---- barrier helpers: per-block flag publish + flat poll-all ----
    bool alive = true;
    auto waitall = [&](unsigned tgt) {
        if (alive && w == 0) {
            int n = 0;
            for (;;) {
                unsigned v0 = ld32a(flags + lane * 16);
                unsigned v1 = 0xFFFFFFFFu;
                if (FULL && lane < 16) v1 = ld32a(flags + (64 + lane) * 16);
                if (__all((v0 >= tgt) && (v1 >= tgt))) break;
                if (++n > (1 << 17)) { alive = false; break; }   // failsafe: no hangs
            }
        }
        __syncthreads();
    };

    // initial publish: zeros + prologue ring visible before flag
    asm volatile("s_waitcnt vmcnt(0)" ::: "memory");
    __syncthreads();
    if (tid == 0) { asm volatile("s_waitcnt vmcnt(0)" ::: "memory"); st32a(flags + bid * 16, 1u); }
    waitall(1u);

    float c4[4] = {0.f, 0.f, 0.f, 0.f};
    f32x4 gnext[4];      // role 0: prefetched ring1 slice
    f32x4 accx[4];       // role 1 (!FULL): slack-computed gx2 slice

    if (role == 0) {     // preload gx1[t=0] (visible after init barrier)
        #pragma unroll
        for (int nt = 0; nt < 4; ++nt)
            #pragma unroll
            for (int rr = 0; rr < 4; ++rr)
                gnext[nt][rr] = ldf32a(ring1 + (bbase + q * 4 + rr) * NG + nt * 256 + u0 + l15);
    }

    for (int e = 0; e < EPOCHS; ++e) {
        const int par_w = e & 1, par_r = (e - 1) & 1;

        // ================= main (critical path) =================
        const bool do_main = (role == 0 && e <= 255) || (role == 1 && e >= 2);
        if (do_main) {
            const unsigned short* hr = (role == 0 ? h1buf : h2buf) + par_r * 16384;
            f32x4 acc[4];
            if (role == 0) {
                #pragma unroll
                for (int nt = 0; nt < 4; ++nt) acc[nt] = gnext[nt];
            } else if (FULL) {
                const float* g2 = ring2 + (long)((e - 2) & 1) * (64 * NG);
                #pragma unroll
                for (int nt = 0; nt < 4; ++nt)
                    #pragma unroll
                    for (int rr = 0; rr < 4; ++rr)
                        acc[nt][rr] = ldf32a(g2 + (bbase + q * 4 + rr) * NG + nt * 256 + u0 + l15);
            } else {
                #pragma unroll
                for (int nt = 0; nt < 4; ++nt) acc[nt] = accx[nt];
            }
            short8 a8[8];
            #pragma unroll
            for (int s = 0; s < 8; ++s)
                a8[s] = ldh16(hr + arow * HIDDEN + s * 32 + q * 8);
            #pragma unroll
            for (int s = 0; s < 8; ++s)
                #pragma unroll
                for (int nt = 0; nt < 4; ++nt)
                    acc[nt] = MFMA(a8[s], bfragR[s][nt], acc[nt]);
            #pragma unroll
            for (int rr = 0; rr < 4; ++rr) {
                int b = bbase + q * 4 + rr;
                float iv = sigm(acc[0][rr]);
                float jv = tanh_(acc[1][rr]);
                float fv = sigm(acc[2][rr] + 1.0f);
                float ov = sigm(acc[3][rr]);
                float cn = c4[rr] * fv + iv * jv;
                c4[rr] = cn;
                float hn = tanh_(cn) * ov;
                *(unsigned short*)((char*)lds + 32768 + (b * 16 + l15) * 2) = f2bf(hn);
                if (role == 1 && e == 257) out[b * HIDDEN + u] = hn;
            }
        } else if (FULL && role == 2 && e >= 1 && e <= 256) {
            // gx2[t=e-1] = b1 + h1[t] @ W1x  -> ring2 slot t&1
            const int t = e - 1;
            const unsigned short* h1r = h1buf + (t & 1) * 16384;
            f32x4 g[4];
            #pragma unroll
            for (int nt = 0; nt < 4; ++nt)
                g[nt] = (f32x4){bias_r[nt], bias_r[nt], bias_r[nt], bias_r[nt]};
            #pragma unroll
            for (int s = 0; s < 8; ++s) {
                short8 a = ldh16(h1r + arow * HIDDEN + s * 32 + q * 8);
                #pragma unroll
                for (int nt = 0; nt < 4; ++nt) {
                    int c = nt * 16 + l15;
                    short8 b = *(const short8*)((char*)lds + s * 4096 + swzb(c, c * 64 + q * 16));
                    g[nt] = MFMA(a, b, g[nt]);
                }
            }
            float* dst = ring2 + (long)(t & 1) * (64 * NG);
            #pragma unroll
            for (int nt = 0; nt < 4; ++nt)
                #pragma unroll
                for (int rr = 0; rr < 4; ++rr)
                    stf32a(dst + (bbase + q * 4 + rr) * NG + nt * 256 + u0 + l15, g[nt][rr]);
        }

        __syncthreads();   // h-stage in LDS ready; main-phase global stores drained

        // publish h from LDS stage as coherent u64 stores (1 per thread)
        if (do_main) {
            unsigned short* hw = (role == 0 ? h1buf : h2buf) + par_w * 16384;
            unsigned long long v = *(unsigned long long*)((char*)lds + 32768 + tid * 8);
            int r = tid >> 2, p = tid & 3;
            st64a((unsigned long long*)(hw + r * HIDDEN + u0) + p, v);
        }
        asm volatile("s_waitcnt vmcnt(0)" ::: "memory");
        __syncthreads();   // all waves' publish stores drained
        if (tid == 0) { asm volatile("s_waitcnt vmcnt(0)" ::: "memory"); st32a(flags + bid * 16, (unsigned)(e + 2)); }

        // ================= slack (off critical path) =================
        if (role == 0 && e + 1 <= 255) {
            const float* g1 = ring1 + (long)((e + 1) & 3) * (64 * NG);
            #pragma unroll
            for (int nt = 0; nt < 4; ++nt)
                #pragma unroll
                for (int rr = 0; rr < 4; ++rr)
                    gnext[nt][rr] = ldf32a(g1 + (bbase + q * 4 + rr) * NG + nt * 256 + u0 + l15);
        } else if (!FULL && role == 1 && e >= 1 && e <= 256) {
            // accx for next epoch: b1 + h1[e-1] @ W1x
            const unsigned short* h1r = h1buf + ((e - 1) & 1) * 16384;
            #pragma unroll
            for (int nt = 0; nt < 4; ++nt)
                accx[nt] = (f32x4){bias_r[nt], bias_r[nt], bias_r[nt], bias_r[nt]};
            #pragma unroll
            for (int s = 0; s < 8; ++s) {
                short8 a = ldh16(h1r + arow * HIDDEN + s * 32 + q * 8);
                #pragma unroll
                for (int nt = 0; nt < 4; ++nt) {
                    int c = nt * 16 + l15;
                    short8 b = *(const short8*)((char*)lds + s * 4096 + swzb(c, c * 64 + q * 16));
                    accx[nt] = MFMA(a, b, accx[nt]);
                }
            }
        } else if (role == 3 && e <= 252) {
            produce(e + 3);
        }

        waitall((unsigned)(e + 2));
    }
}

__global__ void ws_too_small_sentinel(float* out, int n) {
    int i = blockIdx.x * 256 + threadIdx.x;
    if (i < n) out[i] = 31337.0f;
}

extern "C" void kernel_launch(void* const* d_in, const int* in_sizes, int n_in,
                              void* d_out, int out_size, void* d_ws, size_t ws_size,
                              hipStream_t stream)
{
    const int*   xin = (const int*)d_in[0];
    const float* emb = (const float*)d_in[1];
    const float* W0  = (const float*)d_in[2];
    const float* b0  = (const float*)d_in[3];
    const float* W1  = (const float*)d_in[4];
    const float* b1  = (const float*)d_in[5];
    float* out = (float*)d_out;

    // layout: h1[128K-aligned base], h2, ring1, flags, [ring2 if FULL]
    const size_t OFF_H1    = 0;
    const size_t OFF_H2    = OFF_H1 + 65536;
    const size_t OFF_RING1 = OFF_H2 + 65536;                  // 1 MB
    const size_t OFF_FLAGS = OFF_RING1 + (size_t)4 * 64 * NG * 4;
    const size_t NEED_FB   = OFF_FLAGS + 4096;                // = 1,183,744 (round-2 proven)
    const size_t OFF_RING2 = OFF_FLAGS + 8192;
    const size_t NEED_FULL = OFF_RING2 + (size_t)2 * 64 * NG * 4;   // = 1,712,128

    if (ws_size < NEED_FB) {
        ws_too_small_sentinel<<<(out_size + 255) / 256, 256, 0, stream>>>(out, out_size);
        return;
    }
    const bool full = (ws_size >= NEED_FULL);

    char* ws = (char*)d_ws;
    unsigned short* h1buf = (unsigned short*)(ws + OFF_H1);
    unsigned short* h2buf = (unsigned short*)(ws + OFF_H2);
    float*          ring1 = (float*)(ws + OFF_RING1);
    unsigned*       flags = (unsigned*)(ws + OFF_FLAGS);
    float*          ring2 = full ? (float*)(ws + OFF_RING2) : ring1;

    hipMemsetAsync(flags, 0, full ? 8192 : 4096, stream);
    if (full) {
        lstm_fused<true><<<dim3(80), dim3(256), 40960, stream>>>(
            xin, emb, W0, b0, W1, b1, flags, h1buf, h2buf, ring1, ring2, out);
    } else {
        lstm_fused<false><<<dim3(64), dim3(256), 40960, stream>>>(
            xin, emb, W0, b0, W1, b1, flags, h1buf, h2buf, ring1, ring2, out);
    }
}